// Round 2
// baseline (897.511 us; speedup 1.0000x reference)
//
#include <hip/hip_runtime.h>
#include <math.h>

// VQ-VAE EMA vector quantizer for MI355X (gfx950).
// Strategy: bit-replicate the numpy-f32 reference computation for the argmin:
//   dists = (sum(x*x) - (2x)@emb.T) + sum(e*e), all f32, numpy pairwise row-sums,
//   BLAS sequential-FMA dot, first-occurrence argmin.
#define NROWS 131072          // 32*4096
#define DIM 64
#define NCODE 512
#define DECAYF 0.9f
#define EPSF 1e-5f

// d_out float offsets (outputs concatenated flat, all float32-viewed)
#define OUT_ZQ    0
#define OUT_LOSS  8388608
#define OUT_CODES 8388609
#define OUT_ECS   8519681
#define OUT_EMAW  8520193
#define OUT_EMB   8552961

// workspace byte offsets
#define WS_LOSS   0        // double
#define WS_N      8        // float
#define WS_COUNTS 16       // float[512]
#define WS_DW     2064     // float[32768]
#define WS_CSUM   133136   // float[512]
#define WS_BYTES  135184

// numpy pairwise sum (scalar unroll-8 path, n=64) of v[d]*v[d], all f32, no contraction.
__device__ __forceinline__ float np_pairwise64_sq(const float* v) {
    float r[8];
#pragma unroll
    for (int j = 0; j < 8; ++j) r[j] = __fmul_rn(v[j], v[j]);
#pragma unroll
    for (int b = 1; b < 8; ++b) {
#pragma unroll
        for (int j = 0; j < 8; ++j)
            r[j] = __fadd_rn(r[j], __fmul_rn(v[8 * b + j], v[8 * b + j]));
    }
    return __fadd_rn(__fadd_rn(__fadd_rn(r[0], r[1]), __fadd_rn(r[2], r[3])),
                     __fadd_rn(__fadd_rn(r[4], r[5]), __fadd_rn(r[6], r[7])));
}

// ---- csum[k] = np.sum(emb[k]*emb[k]) with numpy pairwise bits ----
__global__ void k_csum(const float* __restrict__ emb, float* __restrict__ csum) {
    int k = blockIdx.x * blockDim.x + threadIdx.x;
    if (k >= NCODE) return;
    float e[DIM];
#pragma unroll
    for (int d = 0; d < DIM; d += 4) {
        float4 v = *reinterpret_cast<const float4*>(emb + (size_t)k * DIM + d);
        e[d] = v.x; e[d + 1] = v.y; e[d + 2] = v.z; e[d + 3] = v.w;
    }
    csum[k] = np_pairwise64_sq(e);
}

// ---- argmin over k of fl(fl(A - dot2_k) + csum_k), replicating numpy f32 ----
__global__ __launch_bounds__(256) void k_scores(
        const float* __restrict__ ze, const float* __restrict__ emb,
        const float* __restrict__ csum, float* __restrict__ codes_f) {
    int row = blockIdx.x * blockDim.x + threadIdx.x;
    if (row >= NROWS) return;
    const float* x = ze + (size_t)row * DIM;
    float x2[DIM];
#pragma unroll
    for (int d = 0; d < DIM; d += 4) {
        float4 v = *reinterpret_cast<const float4*>(x + d);
        x2[d]     = __fadd_rn(v.x, v.x);
        x2[d + 1] = __fadd_rn(v.y, v.y);
        x2[d + 2] = __fadd_rn(v.z, v.z);
        x2[d + 3] = __fadd_rn(v.w, v.w);
    }
    // sum((2x)^2) = 4*sum(x^2) bit-exactly (power-of-2 scaling commutes with rounding)
    float A = __fmul_rn(0.25f, np_pairwise64_sq(x2));

    float m1 = 3.4e38f;
    int i1 = 0;
    for (int k = 0; k < NCODE; k += 4) {
        const float* e = emb + (size_t)k * DIM;     // wave-uniform -> scalar loads
        float a0 = 0.f, a1 = 0.f, a2 = 0.f, a3 = 0.f;
#pragma unroll
        for (int d = 0; d < DIM; ++d) {             // BLAS microkernel: sequential FMA over K
            a0 = __builtin_fmaf(x2[d], e[d], a0);
            a1 = __builtin_fmaf(x2[d], e[d + 64], a1);
            a2 = __builtin_fmaf(x2[d], e[d + 128], a2);
            a3 = __builtin_fmaf(x2[d], e[d + 192], a3);
        }
        float t0 = __fadd_rn(__fsub_rn(A, a0), csum[k + 0]);
        float t1 = __fadd_rn(__fsub_rn(A, a1), csum[k + 1]);
        float t2 = __fadd_rn(__fsub_rn(A, a2), csum[k + 2]);
        float t3 = __fadd_rn(__fsub_rn(A, a3), csum[k + 3]);
        if (t0 < m1) { m1 = t0; i1 = k; }           // strict < keeps first occurrence
        if (t1 < m1) { m1 = t1; i1 = k + 1; }
        if (t2 < m1) { m1 = t2; i1 = k + 2; }
        if (t3 < m1) { m1 = t3; i1 = k + 3; }
    }
    codes_f[row] = (float)i1;
}

// ---- apply: z_q_st, loss accumulation, dw/counts scatter ----
__global__ __launch_bounds__(256) void k_apply(
        const float* __restrict__ ze, const float* __restrict__ emb,
        const float* __restrict__ codes_f, float* __restrict__ out,
        float* __restrict__ counts, float* __restrict__ dw,
        double* __restrict__ lossAcc) {
    int row = blockIdx.x * blockDim.x + threadIdx.x;
    double lsum = 0.0;
    if (row < NROWS) {
        int code = (int)codes_f[row];
        const float* x = ze + (size_t)row * DIM;
        const float* e = emb + (size_t)code * DIM;
        float* zq = out + OUT_ZQ + (size_t)row * DIM;
#pragma unroll
        for (int d = 0; d < DIM; d += 4) {
            float4 xv = *reinterpret_cast<const float4*>(x + d);
            float4 ev = *reinterpret_cast<const float4*>(e + d);
            float4 o;
            o.x = __fadd_rn(xv.x, __fsub_rn(ev.x, xv.x));   // z_e + (z_q - z_e), f32 like ref
            o.y = __fadd_rn(xv.y, __fsub_rn(ev.y, xv.y));
            o.z = __fadd_rn(xv.z, __fsub_rn(ev.z, xv.z));
            o.w = __fadd_rn(xv.w, __fsub_rn(ev.w, xv.w));
            *reinterpret_cast<float4*>(zq + d) = o;
            float q0 = xv.x - ev.x, q1 = xv.y - ev.y, q2 = xv.z - ev.z, q3 = xv.w - ev.w;
            lsum += (double)q0 * q0 + (double)q1 * q1 + (double)q2 * q2 + (double)q3 * q3;
            atomicAdd(&dw[code * DIM + d + 0], xv.x);
            atomicAdd(&dw[code * DIM + d + 1], xv.y);
            atomicAdd(&dw[code * DIM + d + 2], xv.z);
            atomicAdd(&dw[code * DIM + d + 3], xv.w);
        }
        atomicAdd(&counts[code], 1.0f);
    }
    for (int off = 32; off; off >>= 1) lsum += __shfl_down(lsum, off);
    __shared__ double ls[4];
    int wid = threadIdx.x >> 6;
    if ((threadIdx.x & 63) == 0) ls[wid] = lsum;
    __syncthreads();
    if (threadIdx.x == 0) {
        double t = (ls[0] + ls[1]) + (ls[2] + ls[3]);
        atomicAdd(lossAcc, t);
    }
}

// ---- new_ecs + n ----
__global__ void k_ecs(const float* __restrict__ ecs_in, const float* __restrict__ counts,
                      float* __restrict__ out, float* __restrict__ n_out) {
    __shared__ float red[NCODE];
    int k = threadIdx.x;
    float v = ecs_in[k] * DECAYF + counts[k] * (1.0f - DECAYF);
    out[OUT_ECS + k] = v;
    red[k] = v;
    __syncthreads();
    for (int s = NCODE / 2; s > 0; s >>= 1) {
        if (k < s) red[k] += red[k + s];
        __syncthreads();
    }
    if (k == 0) n_out[0] = red[0];
}

// ---- new_ema_w, new_emb, loss ----
__global__ __launch_bounds__(256) void k_final(
        const float* __restrict__ ema_w, const float* __restrict__ dw,
        const float* __restrict__ n_ptr, const double* __restrict__ lossAcc,
        float* __restrict__ out) {
    int i = blockIdx.x * blockDim.x + threadIdx.x;
    if (i >= NCODE * DIM) return;
    int k = i >> 6;
    float w = ema_w[i] * DECAYF + dw[i] * (1.0f - DECAYF);
    out[OUT_EMAW + i] = w;
    float n = n_ptr[0];
    float necs = out[OUT_ECS + k];
    float cs = (necs + EPSF) / (n + (float)NCODE * EPSF) * n;
    out[OUT_EMB + i] = w / (cs + EPSF);
    if (i == 0) out[OUT_LOSS] = (float)(0.1 * (lossAcc[0] / (double)((size_t)NROWS * DIM)));
}

extern "C" void kernel_launch(void* const* d_in, const int* in_sizes, int n_in,
                              void* d_out, int out_size, void* d_ws, size_t ws_size,
                              hipStream_t stream) {
    const float* ze   = (const float*)d_in[0];
    const float* emb  = (const float*)d_in[1];
    const float* ecs  = (const float*)d_in[2];
    const float* emaw = (const float*)d_in[3];
    float* out = (float*)d_out;
    char* ws = (char*)d_ws;
    double* lossAcc = (double*)(ws + WS_LOSS);
    float*  n_out   = (float*)(ws + WS_N);
    float*  counts  = (float*)(ws + WS_COUNTS);
    float*  dw      = (float*)(ws + WS_DW);
    float*  csum    = (float*)(ws + WS_CSUM);

    hipMemsetAsync(d_ws, 0, WS_BYTES, stream);
    hipLaunchKernelGGL(k_csum, dim3(2), dim3(256), 0, stream, emb, csum);
    hipLaunchKernelGGL(k_scores, dim3(NROWS / 256), dim3(256), 0, stream,
                       ze, emb, csum, out + OUT_CODES);
    hipLaunchKernelGGL(k_apply, dim3(NROWS / 256), dim3(256), 0, stream,
                       ze, emb, out + OUT_CODES, out, counts, dw, lossAcc);
    hipLaunchKernelGGL(k_ecs, dim3(1), dim3(NCODE), 0, stream, ecs, counts, out, n_out);
    hipLaunchKernelGGL(k_final, dim3(NCODE * DIM / 256), dim3(256), 0, stream,
                       emaw, dw, n_out, lossAcc, out);
}

// Round 3
// 427.620 us; speedup vs baseline: 2.0989x; 2.0989x over previous
//
#include <hip/hip_runtime.h>
#include <math.h>

// VQ-VAE EMA vector quantizer for MI355X (gfx950).
// Argmin bit-replicates the numpy-f32 reference: dists = (sum(x*x) - (2x)@emb.T) + sum(e*e),
// numpy pairwise row-sums, BLAS sequential-FMA dot, first-occurrence argmin.
// dw/counts via counting-sort segmented reduction (no f32 global atomics).
#define NROWS 131072          // 32*4096
#define DIM 64
#define NCODE 512

// d_out float offsets (outputs concatenated flat, all float32-viewed)
#define OUT_ZQ    0
#define OUT_LOSS  8388608
#define OUT_CODES 8388609
#define OUT_ECS   8519681
#define OUT_EMAW  8520193
#define OUT_EMB   8552961

// workspace byte offsets
#define WS_LOSS    0         // double
#define WS_N       8         // float
#define WS_COUNTS  16        // int[512]
#define WS_OFFSETS 2064      // int[512]
#define WS_CURSOR  4112      // int[512]
#define WS_CSUM    6160      // float[512]
#define WS_CODESI  8208      // int[131072]
#define WS_BUCKET  532496    // int[131072]
#define WS_DW      1056784   // float[32768]
#define WS_BYTES   1187856
#define WS_ZERO_BYTES 2064   // loss + n + counts

// reference scalar constants, rounded exactly as jax/numpy round them (f64 -> f32)
#define DECAY_C ((float)0.9)
#define OMD_C   ((float)(1.0 - 0.9))
#define EPS_C   ((float)1e-5)

// numpy pairwise sum (scalar unroll-8 path, n=64) of v[d]*v[d], all f32, no contraction.
__device__ __forceinline__ float np_pairwise64_sq(const float* v) {
    float r[8];
#pragma unroll
    for (int j = 0; j < 8; ++j) r[j] = __fmul_rn(v[j], v[j]);
#pragma unroll
    for (int b = 1; b < 8; ++b) {
#pragma unroll
        for (int j = 0; j < 8; ++j)
            r[j] = __fadd_rn(r[j], __fmul_rn(v[8 * b + j], v[8 * b + j]));
    }
    return __fadd_rn(__fadd_rn(__fadd_rn(r[0], r[1]), __fadd_rn(r[2], r[3])),
                     __fadd_rn(__fadd_rn(r[4], r[5]), __fadd_rn(r[6], r[7])));
}

// ---- csum[k] = np.sum(emb[k]*emb[k]) with numpy pairwise bits ----
__global__ void k_csum(const float* __restrict__ emb, float* __restrict__ csum) {
    int k = blockIdx.x * blockDim.x + threadIdx.x;
    if (k >= NCODE) return;
    float e[DIM];
#pragma unroll
    for (int d = 0; d < DIM; d += 4) {
        float4 v = *reinterpret_cast<const float4*>(emb + (size_t)k * DIM + d);
        e[d] = v.x; e[d + 1] = v.y; e[d + 2] = v.z; e[d + 3] = v.w;
    }
    csum[k] = np_pairwise64_sq(e);
}

// ---- fused: argmin + codes + z_q + loss + LDS histogram ----
__global__ __launch_bounds__(256) void k_scores(
        const float* __restrict__ ze, const float* __restrict__ emb,
        const float* __restrict__ csum, float* __restrict__ out,
        int* __restrict__ codes_i, int* __restrict__ counts,
        double* __restrict__ lossAcc) {
    __shared__ int h[NCODE];
    __shared__ double ls[4];
    for (int i = threadIdx.x; i < NCODE; i += 256) h[i] = 0;
    __syncthreads();

    int row = blockIdx.x * 256 + threadIdx.x;
    const float* x = ze + (size_t)row * DIM;
    float x2[DIM];
#pragma unroll
    for (int d = 0; d < DIM; d += 4) {
        float4 v = *reinterpret_cast<const float4*>(x + d);
        x2[d]     = __fadd_rn(v.x, v.x);
        x2[d + 1] = __fadd_rn(v.y, v.y);
        x2[d + 2] = __fadd_rn(v.z, v.z);
        x2[d + 3] = __fadd_rn(v.w, v.w);
    }
    // sum((2x)^2) = 4*sum(x^2) bit-exactly (power-of-2 scaling commutes with rounding)
    float A = __fmul_rn(0.25f, np_pairwise64_sq(x2));

    float m1 = 3.4e38f;
    int i1 = 0;
    for (int k = 0; k < NCODE; k += 8) {
        const float* e = emb + (size_t)k * DIM;     // wave-uniform -> scalar loads
        float a0 = 0.f, a1 = 0.f, a2 = 0.f, a3 = 0.f;
        float a4 = 0.f, a5 = 0.f, a6 = 0.f, a7 = 0.f;
#pragma unroll
        for (int d = 0; d < DIM; ++d) {             // BLAS microkernel: sequential FMA per code
            float xv = x2[d];
            a0 = __builtin_fmaf(xv, e[d], a0);
            a1 = __builtin_fmaf(xv, e[d + 64], a1);
            a2 = __builtin_fmaf(xv, e[d + 128], a2);
            a3 = __builtin_fmaf(xv, e[d + 192], a3);
            a4 = __builtin_fmaf(xv, e[d + 256], a4);
            a5 = __builtin_fmaf(xv, e[d + 320], a5);
            a6 = __builtin_fmaf(xv, e[d + 384], a6);
            a7 = __builtin_fmaf(xv, e[d + 448], a7);
        }
        float t0 = __fadd_rn(__fsub_rn(A, a0), csum[k + 0]);
        float t1 = __fadd_rn(__fsub_rn(A, a1), csum[k + 1]);
        float t2 = __fadd_rn(__fsub_rn(A, a2), csum[k + 2]);
        float t3 = __fadd_rn(__fsub_rn(A, a3), csum[k + 3]);
        float t4 = __fadd_rn(__fsub_rn(A, a4), csum[k + 4]);
        float t5 = __fadd_rn(__fsub_rn(A, a5), csum[k + 5]);
        float t6 = __fadd_rn(__fsub_rn(A, a6), csum[k + 6]);
        float t7 = __fadd_rn(__fsub_rn(A, a7), csum[k + 7]);
        if (t0 < m1) { m1 = t0; i1 = k; }           // strict < keeps first occurrence
        if (t1 < m1) { m1 = t1; i1 = k + 1; }
        if (t2 < m1) { m1 = t2; i1 = k + 2; }
        if (t3 < m1) { m1 = t3; i1 = k + 3; }
        if (t4 < m1) { m1 = t4; i1 = k + 4; }
        if (t5 < m1) { m1 = t5; i1 = k + 5; }
        if (t6 < m1) { m1 = t6; i1 = k + 6; }
        if (t7 < m1) { m1 = t7; i1 = k + 7; }
    }
    out[OUT_CODES + row] = (float)i1;
    codes_i[row] = i1;
    atomicAdd(&h[i1], 1);                           // LDS atomic

    // z_q = x + (e - x), loss accumulation; x recovered exactly as 0.5*x2
    const float* e1 = emb + (size_t)i1 * DIM;
    float* zq = out + OUT_ZQ + (size_t)row * DIM;
    double lsum = 0.0;
#pragma unroll
    for (int d = 0; d < DIM; d += 4) {
        float4 ev = *reinterpret_cast<const float4*>(e1 + d);
        float xa = __fmul_rn(0.5f, x2[d]);
        float xb = __fmul_rn(0.5f, x2[d + 1]);
        float xc = __fmul_rn(0.5f, x2[d + 2]);
        float xd = __fmul_rn(0.5f, x2[d + 3]);
        float ta = __fsub_rn(ev.x, xa);
        float tb = __fsub_rn(ev.y, xb);
        float tc = __fsub_rn(ev.z, xc);
        float td = __fsub_rn(ev.w, xd);
        float4 o;
        o.x = __fadd_rn(xa, ta);
        o.y = __fadd_rn(xb, tb);
        o.z = __fadd_rn(xc, tc);
        o.w = __fadd_rn(xd, td);
        *reinterpret_cast<float4*>(zq + d) = o;
        lsum += (double)ta * ta + (double)tb * tb + (double)tc * tc + (double)td * td;
    }
    for (int off = 32; off; off >>= 1) lsum += __shfl_down(lsum, off);
    int wid = threadIdx.x >> 6;
    if ((threadIdx.x & 63) == 0) ls[wid] = lsum;
    __syncthreads();                                // also orders LDS histogram
    if (threadIdx.x == 0)
        atomicAdd(lossAcc, (ls[0] + ls[1]) + (ls[2] + ls[3]));
    for (int k = threadIdx.x; k < NCODE; k += 256) {
        int c = h[k];
        if (c) atomicAdd(&counts[k], c);            // int global atomic, aggregated
    }
}

// ---- one block: exclusive scan of counts -> offsets/cursor; new_ecs + n ----
__global__ __launch_bounds__(512) void k_scan(
        const int* __restrict__ counts, int* __restrict__ offsets, int* __restrict__ cursor,
        const float* __restrict__ ecs_in, float* __restrict__ out, float* __restrict__ n_out) {
    __shared__ int sa[NCODE], sb[NCODE];
    __shared__ float red[NCODE];
    int k = threadIdx.x;
    int c = counts[k];
    sa[k] = c;
    float v = __fadd_rn(__fmul_rn(ecs_in[k], DECAY_C), __fmul_rn((float)c, OMD_C));
    out[OUT_ECS + k] = v;
    red[k] = v;
    __syncthreads();
    int* src = sa;
    int* dst = sb;
    for (int off = 1; off < NCODE; off <<= 1) {
        dst[k] = (k >= off) ? src[k - off] + src[k] : src[k];
        __syncthreads();
        int* t = src; src = dst; dst = t;
    }
    offsets[k] = src[k] - c;
    cursor[k]  = src[k] - c;
    for (int s = NCODE / 2; s > 0; s >>= 1) {
        if (k < s) red[k] += red[k + s];
        __syncthreads();
    }
    if (k == 0) n_out[0] = red[0];
}

// ---- scatter rows into code buckets ----
__global__ __launch_bounds__(256) void k_scatter(
        const int* __restrict__ codes_i, int* __restrict__ cursor, int* __restrict__ bucket) {
    int row = blockIdx.x * 256 + threadIdx.x;
    int c = codes_i[row];
    int pos = atomicAdd(&cursor[c], 1);
    bucket[pos] = row;
}

// ---- per-code segmented sum: dw[k][d] = sum of ze rows in bucket k (no atomics) ----
__global__ __launch_bounds__(64) void k_dw(
        const float* __restrict__ ze, const int* __restrict__ bucket,
        const int* __restrict__ offsets, const int* __restrict__ counts,
        float* __restrict__ dw) {
    int k = blockIdx.x;
    int d = threadIdx.x;
    int s = offsets[k];
    int n = counts[k];
    float acc = 0.f;
    int i = 0;
    for (; i + 4 <= n; i += 4) {
        int r0 = bucket[s + i + 0];
        int r1 = bucket[s + i + 1];
        int r2 = bucket[s + i + 2];
        int r3 = bucket[s + i + 3];
        float v0 = ze[(size_t)r0 * DIM + d];
        float v1 = ze[(size_t)r1 * DIM + d];
        float v2 = ze[(size_t)r2 * DIM + d];
        float v3 = ze[(size_t)r3 * DIM + d];
        acc += v0; acc += v1; acc += v2; acc += v3;
    }
    for (; i < n; ++i) acc += ze[(size_t)bucket[s + i] * DIM + d];
    dw[k * DIM + d] = acc;
}

// ---- new_ema_w, new_emb, loss ----
__global__ __launch_bounds__(256) void k_final(
        const float* __restrict__ ema_w, const float* __restrict__ dw,
        const float* __restrict__ n_ptr, const double* __restrict__ lossAcc,
        float* __restrict__ out) {
    int i = blockIdx.x * blockDim.x + threadIdx.x;
    if (i >= NCODE * DIM) return;
    int k = i >> 6;
    float w = __fadd_rn(__fmul_rn(ema_w[i], DECAY_C), __fmul_rn(dw[i], OMD_C));
    out[OUT_EMAW + i] = w;
    float n = n_ptr[0];
    float necs = out[OUT_ECS + k];
    float cs = (necs + EPS_C) / (n + (float)NCODE * EPS_C) * n;
    out[OUT_EMB + i] = w / (cs + EPS_C);
    if (i == 0) out[OUT_LOSS] = (float)(0.1 * (lossAcc[0] / (double)((size_t)NROWS * DIM)));
}

extern "C" void kernel_launch(void* const* d_in, const int* in_sizes, int n_in,
                              void* d_out, int out_size, void* d_ws, size_t ws_size,
                              hipStream_t stream) {
    const float* ze   = (const float*)d_in[0];
    const float* emb  = (const float*)d_in[1];
    const float* ecs  = (const float*)d_in[2];
    const float* emaw = (const float*)d_in[3];
    float* out = (float*)d_out;
    char* ws = (char*)d_ws;
    double* lossAcc = (double*)(ws + WS_LOSS);
    float*  n_out   = (float*)(ws + WS_N);
    int*    counts  = (int*)(ws + WS_COUNTS);
    int*    offsets = (int*)(ws + WS_OFFSETS);
    int*    cursor  = (int*)(ws + WS_CURSOR);
    float*  csum    = (float*)(ws + WS_CSUM);
    int*    codes_i = (int*)(ws + WS_CODESI);
    int*    bucket  = (int*)(ws + WS_BUCKET);
    float*  dw      = (float*)(ws + WS_DW);

    hipMemsetAsync(d_ws, 0, WS_ZERO_BYTES, stream);
    hipLaunchKernelGGL(k_csum, dim3(2), dim3(256), 0, stream, emb, csum);
    hipLaunchKernelGGL(k_scores, dim3(NROWS / 256), dim3(256), 0, stream,
                       ze, emb, csum, out, codes_i, counts, lossAcc);
    hipLaunchKernelGGL(k_scan, dim3(1), dim3(512), 0, stream,
                       counts, offsets, cursor, ecs, out, n_out);
    hipLaunchKernelGGL(k_scatter, dim3(NROWS / 256), dim3(256), 0, stream,
                       codes_i, cursor, bucket);
    hipLaunchKernelGGL(k_dw, dim3(NCODE), dim3(64), 0, stream,
                       ze, bucket, offsets, counts, dw);
    hipLaunchKernelGGL(k_final, dim3(NCODE * DIM / 256), dim3(256), 0, stream,
                       emaw, dw, n_out, lossAcc, out);
}

// Round 4
// 399.037 us; speedup vs baseline: 2.2492x; 1.0716x over previous
//
#include <hip/hip_runtime.h>
#include <math.h>

// VQ-VAE EMA vector quantizer for MI355X (gfx950).
// Argmin bit-replicates the numpy-f32 reference: dists = (sum(x*x) - (2x)@emb.T) + sum(e*e),
// numpy pairwise row-sums, BLAS sequential-FMA dot, first-occurrence argmin.
// dw/counts via counting-sort segmented reduction (no f32 global atomics).
// Round 4: force x2 into VGPRs (ext_vector + macro-constant indices); 4-wave k_dw.
#define NROWS 131072          // 32*4096
#define DIM 64
#define NCODE 512

// d_out float offsets (outputs concatenated flat, all float32-viewed)
#define OUT_ZQ    0
#define OUT_LOSS  8388608
#define OUT_CODES 8388609
#define OUT_ECS   8519681
#define OUT_EMAW  8520193
#define OUT_EMB   8552961

// workspace byte offsets
#define WS_LOSS    0         // double
#define WS_N       8         // float
#define WS_COUNTS  16        // int[512]
#define WS_OFFSETS 2064      // int[512]
#define WS_CURSOR  4112      // int[512]
#define WS_CSUM    6160      // float[512]
#define WS_CODESI  8208      // int[131072]
#define WS_BUCKET  532496    // int[131072]
#define WS_DW      1056784   // float[32768]
#define WS_BYTES   1187856
#define WS_ZERO_BYTES 2064   // loss + n + counts

// reference scalar constants
#define DECAY_C ((float)0.9)
#define OMD_C   ((float)(1.0 - 0.9))
#define EPS_C   ((float)1e-5)

typedef float f32x64 __attribute__((ext_vector_type(64)));

// repetition macros (all indices compile-time constants -> vector stays in VGPRs)
#define R4(M, b)  M(b) M((b) + 1) M((b) + 2) M((b) + 3)
#define R8(M, b)  R4(M, b) R4(M, (b) + 4)
#define R16(M, b) R4(M, b) R4(M, (b) + 4) R4(M, (b) + 8) R4(M, (b) + 12)
#define R64(M)    R16(M, 0) R16(M, 16) R16(M, 32) R16(M, 48)

// numpy pairwise sum (scalar unroll-8 path, n=64) of v[d]*v[d], f32, no contraction.
__device__ __forceinline__ float np_pairwise64_sq(const float* v) {
    float r[8];
#pragma unroll
    for (int j = 0; j < 8; ++j) r[j] = __fmul_rn(v[j], v[j]);
#pragma unroll
    for (int b = 1; b < 8; ++b) {
#pragma unroll
        for (int j = 0; j < 8; ++j)
            r[j] = __fadd_rn(r[j], __fmul_rn(v[8 * b + j], v[8 * b + j]));
    }
    return __fadd_rn(__fadd_rn(__fadd_rn(r[0], r[1]), __fadd_rn(r[2], r[3])),
                     __fadd_rn(__fadd_rn(r[4], r[5]), __fadd_rn(r[6], r[7])));
}

// ---- csum[k] = np.sum(emb[k]*emb[k]) with numpy pairwise bits ----
__global__ void k_csum(const float* __restrict__ emb, float* __restrict__ csum) {
    int k = blockIdx.x * blockDim.x + threadIdx.x;
    if (k >= NCODE) return;
    float e[DIM];
#pragma unroll
    for (int d = 0; d < DIM; d += 4) {
        float4 v = *reinterpret_cast<const float4*>(emb + (size_t)k * DIM + d);
        e[d] = v.x; e[d + 1] = v.y; e[d + 2] = v.z; e[d + 3] = v.w;
    }
    csum[k] = np_pairwise64_sq(e);
}

// ---- fused: argmin + codes + z_q + loss + LDS histogram ----
__global__ __launch_bounds__(256) void k_scores(
        const float* __restrict__ ze, const float* __restrict__ emb,
        const float* __restrict__ csum, float* __restrict__ out,
        int* __restrict__ codes_i, int* __restrict__ counts,
        double* __restrict__ lossAcc) {
    __shared__ int h[NCODE];
    __shared__ double ls[4];
    for (int i = threadIdx.x; i < NCODE; i += 256) h[i] = 0;
    __syncthreads();

    int row = blockIdx.x * 256 + threadIdx.x;
    const float* x = ze + (size_t)row * DIM;
    f32x64 X;   // 2*x, kept in 64 VGPRs (constant indices only)
#define LOADX(q) { \
        float4 v = *reinterpret_cast<const float4*>(x + 4 * (q)); \
        X[4 * (q) + 0] = __fadd_rn(v.x, v.x); \
        X[4 * (q) + 1] = __fadd_rn(v.y, v.y); \
        X[4 * (q) + 2] = __fadd_rn(v.z, v.z); \
        X[4 * (q) + 3] = __fadd_rn(v.w, v.w); }
    R16(LOADX, 0)

    // numpy pairwise sum of (2x)^2; A = sum(x^2) = 0.25*sum((2x)^2) bit-exactly
    float r0 = __fmul_rn(X[0], X[0]), r1 = __fmul_rn(X[1], X[1]);
    float r2 = __fmul_rn(X[2], X[2]), r3 = __fmul_rn(X[3], X[3]);
    float r4 = __fmul_rn(X[4], X[4]), r5 = __fmul_rn(X[5], X[5]);
    float r6 = __fmul_rn(X[6], X[6]), r7 = __fmul_rn(X[7], X[7]);
#define PACC(b) \
    r0 = __fadd_rn(r0, __fmul_rn(X[8 * (b) + 0], X[8 * (b) + 0])); \
    r1 = __fadd_rn(r1, __fmul_rn(X[8 * (b) + 1], X[8 * (b) + 1])); \
    r2 = __fadd_rn(r2, __fmul_rn(X[8 * (b) + 2], X[8 * (b) + 2])); \
    r3 = __fadd_rn(r3, __fmul_rn(X[8 * (b) + 3], X[8 * (b) + 3])); \
    r4 = __fadd_rn(r4, __fmul_rn(X[8 * (b) + 4], X[8 * (b) + 4])); \
    r5 = __fadd_rn(r5, __fmul_rn(X[8 * (b) + 5], X[8 * (b) + 5])); \
    r6 = __fadd_rn(r6, __fmul_rn(X[8 * (b) + 6], X[8 * (b) + 6])); \
    r7 = __fadd_rn(r7, __fmul_rn(X[8 * (b) + 7], X[8 * (b) + 7]));
    PACC(1) PACC(2) PACC(3) PACC(4) PACC(5) PACC(6) PACC(7)
    float A = __fmul_rn(0.25f,
        __fadd_rn(__fadd_rn(__fadd_rn(r0, r1), __fadd_rn(r2, r3)),
                  __fadd_rn(__fadd_rn(r4, r5), __fadd_rn(r6, r7))));

    float m1 = 3.4e38f;
    int i1 = 0;
#define FMA_D(dd) { const float xv = X[dd]; \
        a0 = __builtin_fmaf(xv, e[(dd)      ], a0); \
        a1 = __builtin_fmaf(xv, e[(dd) +  64], a1); \
        a2 = __builtin_fmaf(xv, e[(dd) + 128], a2); \
        a3 = __builtin_fmaf(xv, e[(dd) + 192], a3); \
        a4 = __builtin_fmaf(xv, e[(dd) + 256], a4); \
        a5 = __builtin_fmaf(xv, e[(dd) + 320], a5); \
        a6 = __builtin_fmaf(xv, e[(dd) + 384], a6); \
        a7 = __builtin_fmaf(xv, e[(dd) + 448], a7); }
    for (int k = 0; k < NCODE; k += 8) {
        const float* e = emb + (size_t)k * DIM;     // wave-uniform -> scalar loads
        float a0 = 0.f, a1 = 0.f, a2 = 0.f, a3 = 0.f;
        float a4 = 0.f, a5 = 0.f, a6 = 0.f, a7 = 0.f;
        R64(FMA_D)                                  // BLAS sequential-FMA per code
        float t0 = __fadd_rn(__fsub_rn(A, a0), csum[k + 0]);
        float t1 = __fadd_rn(__fsub_rn(A, a1), csum[k + 1]);
        float t2 = __fadd_rn(__fsub_rn(A, a2), csum[k + 2]);
        float t3 = __fadd_rn(__fsub_rn(A, a3), csum[k + 3]);
        float t4 = __fadd_rn(__fsub_rn(A, a4), csum[k + 4]);
        float t5 = __fadd_rn(__fsub_rn(A, a5), csum[k + 5]);
        float t6 = __fadd_rn(__fsub_rn(A, a6), csum[k + 6]);
        float t7 = __fadd_rn(__fsub_rn(A, a7), csum[k + 7]);
        if (t0 < m1) { m1 = t0; i1 = k; }           // strict < keeps first occurrence
        if (t1 < m1) { m1 = t1; i1 = k + 1; }
        if (t2 < m1) { m1 = t2; i1 = k + 2; }
        if (t3 < m1) { m1 = t3; i1 = k + 3; }
        if (t4 < m1) { m1 = t4; i1 = k + 4; }
        if (t5 < m1) { m1 = t5; i1 = k + 5; }
        if (t6 < m1) { m1 = t6; i1 = k + 6; }
        if (t7 < m1) { m1 = t7; i1 = k + 7; }
    }
    out[OUT_CODES + row] = (float)i1;
    codes_i[row] = i1;
    atomicAdd(&h[i1], 1);                           // LDS atomic

    // z_q = x + (e - x), loss accumulation; x recovered exactly as 0.5*(2x)
    const float* e1 = emb + (size_t)i1 * DIM;
    float* zq = out + OUT_ZQ + (size_t)row * DIM;
    double lsum = 0.0;
#define ZQ4(q) { \
        float4 ev = *reinterpret_cast<const float4*>(e1 + 4 * (q)); \
        float xa = __fmul_rn(0.5f, X[4 * (q) + 0]); \
        float xb = __fmul_rn(0.5f, X[4 * (q) + 1]); \
        float xc = __fmul_rn(0.5f, X[4 * (q) + 2]); \
        float xd = __fmul_rn(0.5f, X[4 * (q) + 3]); \
        float ta = __fsub_rn(ev.x, xa); \
        float tb = __fsub_rn(ev.y, xb); \
        float tc = __fsub_rn(ev.z, xc); \
        float td = __fsub_rn(ev.w, xd); \
        float4 o; \
        o.x = __fadd_rn(xa, ta); \
        o.y = __fadd_rn(xb, tb); \
        o.z = __fadd_rn(xc, tc); \
        o.w = __fadd_rn(xd, td); \
        *reinterpret_cast<float4*>(zq + 4 * (q)) = o; \
        lsum += (double)ta * ta + (double)tb * tb + (double)tc * tc + (double)td * td; }
    R16(ZQ4, 0)

    for (int off = 32; off; off >>= 1) lsum += __shfl_down(lsum, off);
    int wid = threadIdx.x >> 6;
    if ((threadIdx.x & 63) == 0) ls[wid] = lsum;
    __syncthreads();                                // also orders LDS histogram
    if (threadIdx.x == 0)
        atomicAdd(lossAcc, (ls[0] + ls[1]) + (ls[2] + ls[3]));
    for (int k = threadIdx.x; k < NCODE; k += 256) {
        int c = h[k];
        if (c) atomicAdd(&counts[k], c);            // int global atomic, aggregated
    }
}

// ---- one block: exclusive scan of counts -> offsets/cursor; new_ecs + n ----
__global__ __launch_bounds__(512) void k_scan(
        const int* __restrict__ counts, int* __restrict__ offsets, int* __restrict__ cursor,
        const float* __restrict__ ecs_in, float* __restrict__ out, float* __restrict__ n_out) {
    __shared__ int sa[NCODE], sb[NCODE];
    __shared__ float red[NCODE];
    int k = threadIdx.x;
    int c = counts[k];
    sa[k] = c;
    float v = __fadd_rn(__fmul_rn(ecs_in[k], DECAY_C), __fmul_rn((float)c, OMD_C));
    out[OUT_ECS + k] = v;
    red[k] = v;
    __syncthreads();
    int* src = sa;
    int* dst = sb;
    for (int off = 1; off < NCODE; off <<= 1) {
        dst[k] = (k >= off) ? src[k - off] + src[k] : src[k];
        __syncthreads();
        int* t = src; src = dst; dst = t;
    }
    offsets[k] = src[k] - c;
    cursor[k]  = src[k] - c;
    for (int s = NCODE / 2; s > 0; s >>= 1) {
        if (k < s) red[k] += red[k + s];
        __syncthreads();
    }
    if (k == 0) n_out[0] = red[0];
}

// ---- scatter rows into code buckets ----
__global__ __launch_bounds__(256) void k_scatter(
        const int* __restrict__ codes_i, int* __restrict__ cursor, int* __restrict__ bucket) {
    int row = blockIdx.x * 256 + threadIdx.x;
    int c = codes_i[row];
    int pos = atomicAdd(&cursor[c], 1);
    bucket[pos] = row;
}

// ---- per-code segmented sum: dw[k][d] = sum of ze rows in bucket k (no atomics) ----
__global__ __launch_bounds__(256) void k_dw(
        const float* __restrict__ ze, const int* __restrict__ bucket,
        const int* __restrict__ offsets, const int* __restrict__ counts,
        float* __restrict__ dw) {
    __shared__ float p[4][DIM];
    int k = blockIdx.x;
    int w = threadIdx.x >> 6;       // wave 0..3
    int d = threadIdx.x & 63;
    int s = offsets[k];
    int n = counts[k];
    float acc0 = 0.f, acc1 = 0.f;
    int i = w;
    for (; i + 4 < n; i += 8) {     // 2 gathers in flight per wave
        int ra = bucket[s + i];
        int rb = bucket[s + i + 4];
        acc0 += ze[(size_t)ra * DIM + d];
        acc1 += ze[(size_t)rb * DIM + d];
    }
    if (i < n) acc0 += ze[(size_t)bucket[s + i] * DIM + d];
    p[w][d] = acc0 + acc1;
    __syncthreads();
    if (w == 0) dw[k * DIM + d] = (p[0][d] + p[1][d]) + (p[2][d] + p[3][d]);
}

// ---- new_ema_w, new_emb, loss ----
__global__ __launch_bounds__(256) void k_final(
        const float* __restrict__ ema_w, const float* __restrict__ dw,
        const float* __restrict__ n_ptr, const double* __restrict__ lossAcc,
        float* __restrict__ out) {
    int i = blockIdx.x * blockDim.x + threadIdx.x;
    if (i >= NCODE * DIM) return;
    int k = i >> 6;
    float w = __fadd_rn(__fmul_rn(ema_w[i], DECAY_C), __fmul_rn(dw[i], OMD_C));
    out[OUT_EMAW + i] = w;
    float n = n_ptr[0];
    float necs = out[OUT_ECS + k];
    float cs = (necs + EPS_C) / (n + (float)NCODE * EPS_C) * n;
    out[OUT_EMB + i] = w / (cs + EPS_C);
    if (i == 0) out[OUT_LOSS] = (float)(0.1 * (lossAcc[0] / (double)((size_t)NROWS * DIM)));
}

extern "C" void kernel_launch(void* const* d_in, const int* in_sizes, int n_in,
                              void* d_out, int out_size, void* d_ws, size_t ws_size,
                              hipStream_t stream) {
    const float* ze   = (const float*)d_in[0];
    const float* emb  = (const float*)d_in[1];
    const float* ecs  = (const float*)d_in[2];
    const float* emaw = (const float*)d_in[3];
    float* out = (float*)d_out;
    char* ws = (char*)d_ws;
    double* lossAcc = (double*)(ws + WS_LOSS);
    float*  n_out   = (float*)(ws + WS_N);
    int*    counts  = (int*)(ws + WS_COUNTS);
    int*    offsets = (int*)(ws + WS_OFFSETS);
    int*    cursor  = (int*)(ws + WS_CURSOR);
    float*  csum    = (float*)(ws + WS_CSUM);
    int*    codes_i = (int*)(ws + WS_CODESI);
    int*    bucket  = (int*)(ws + WS_BUCKET);
    float*  dw      = (float*)(ws + WS_DW);

    hipMemsetAsync(d_ws, 0, WS_ZERO_BYTES, stream);
    hipLaunchKernelGGL(k_csum, dim3(2), dim3(256), 0, stream, emb, csum);
    hipLaunchKernelGGL(k_scores, dim3(NROWS / 256), dim3(256), 0, stream,
                       ze, emb, csum, out, codes_i, counts, lossAcc);
    hipLaunchKernelGGL(k_scan, dim3(1), dim3(512), 0, stream,
                       counts, offsets, cursor, ecs, out, n_out);
    hipLaunchKernelGGL(k_scatter, dim3(NROWS / 256), dim3(256), 0, stream,
                       codes_i, cursor, bucket);
    hipLaunchKernelGGL(k_dw, dim3(NCODE), dim3(256), 0, stream,
                       ze, bucket, offsets, counts, dw);
    hipLaunchKernelGGL(k_final, dim3(NCODE * DIM / 256), dim3(256), 0, stream,
                       emaw, dw, n_out, lossAcc, out);
}

// Round 5
// 399.014 us; speedup vs baseline: 2.2493x; 1.0001x over previous
//
#include <hip/hip_runtime.h>
#include <math.h>

// VQ-VAE EMA vector quantizer for MI355X (gfx950).
// Argmin bit-replicates the numpy-f32 reference: dists = (sum(x*x) - (2x)@emb.T) + sum(e*e),
// numpy pairwise row-sums, BLAS sequential-FMA dot, first-occurrence argmin.
// dw/counts via counting-sort segmented reduction (no f32 global atomics).
// Round 5: X in 4x f32x16 ext_vectors (v64f32 has no AMDGPU register class -> was scratch).
#define NROWS 131072          // 32*4096
#define DIM 64
#define NCODE 512

// d_out float offsets (outputs concatenated flat, all float32-viewed)
#define OUT_ZQ    0
#define OUT_LOSS  8388608
#define OUT_CODES 8388609
#define OUT_ECS   8519681
#define OUT_EMAW  8520193
#define OUT_EMB   8552961

// workspace byte offsets
#define WS_LOSS    0         // double
#define WS_N       8         // float
#define WS_COUNTS  16        // int[512]
#define WS_OFFSETS 2064      // int[512]
#define WS_CURSOR  4112      // int[512]
#define WS_CSUM    6160      // float[512]
#define WS_CODESI  8208      // int[131072]
#define WS_BUCKET  532496    // int[131072]
#define WS_DW      1056784   // float[32768]
#define WS_BYTES   1187856
#define WS_ZERO_BYTES 2064   // loss + n + counts

// reference scalar constants
#define DECAY_C ((float)0.9)
#define OMD_C   ((float)(1.0 - 0.9))
#define EPS_C   ((float)1e-5)

typedef float f32x16 __attribute__((ext_vector_type(16)));

// repetition macros (all indices literal constants)
#define R4(M, b)  M(b) M((b) + 1) M((b) + 2) M((b) + 3)
#define R16(M, b) R4(M, b) R4(M, (b) + 4) R4(M, (b) + 8) R4(M, (b) + 12)

// numpy pairwise sum (scalar unroll-8 path, n=64) of v[d]*v[d], f32, no contraction.
__device__ __forceinline__ float np_pairwise64_sq(const float* v) {
    float r[8];
#pragma unroll
    for (int j = 0; j < 8; ++j) r[j] = __fmul_rn(v[j], v[j]);
#pragma unroll
    for (int b = 1; b < 8; ++b) {
#pragma unroll
        for (int j = 0; j < 8; ++j)
            r[j] = __fadd_rn(r[j], __fmul_rn(v[8 * b + j], v[8 * b + j]));
    }
    return __fadd_rn(__fadd_rn(__fadd_rn(r[0], r[1]), __fadd_rn(r[2], r[3])),
                     __fadd_rn(__fadd_rn(r[4], r[5]), __fadd_rn(r[6], r[7])));
}

// ---- csum[k] = np.sum(emb[k]*emb[k]) with numpy pairwise bits ----
__global__ void k_csum(const float* __restrict__ emb, float* __restrict__ csum) {
    int k = blockIdx.x * blockDim.x + threadIdx.x;
    if (k >= NCODE) return;
    float e[DIM];
#pragma unroll
    for (int d = 0; d < DIM; d += 4) {
        float4 v = *reinterpret_cast<const float4*>(emb + (size_t)k * DIM + d);
        e[d] = v.x; e[d + 1] = v.y; e[d + 2] = v.z; e[d + 3] = v.w;
    }
    csum[k] = np_pairwise64_sq(e);
}

// ---- fused: argmin + codes + z_q + loss + LDS histogram ----
__global__ __launch_bounds__(256) void k_scores(
        const float* __restrict__ ze, const float* __restrict__ emb,
        const float* __restrict__ csum, float* __restrict__ out,
        int* __restrict__ codes_i, int* __restrict__ counts,
        double* __restrict__ lossAcc) {
    __shared__ int h[NCODE];
    __shared__ double ls[4];
    for (int i = threadIdx.x; i < NCODE; i += 256) h[i] = 0;
    __syncthreads();

    int row = blockIdx.x * 256 + threadIdx.x;
    const float* x = ze + (size_t)row * DIM;
    f32x16 X0, X1, X2, X3;   // 2*x in 64 VGPRs; f32x16 has a register class (VReg_512)
#define LOADQ(V, b, q) { \
        float4 v = *reinterpret_cast<const float4*>(x + 4 * (q)); \
        V[(b) + 0] = __fadd_rn(v.x, v.x); \
        V[(b) + 1] = __fadd_rn(v.y, v.y); \
        V[(b) + 2] = __fadd_rn(v.z, v.z); \
        V[(b) + 3] = __fadd_rn(v.w, v.w); }
    LOADQ(X0, 0, 0)  LOADQ(X0, 4, 1)  LOADQ(X0, 8, 2)  LOADQ(X0, 12, 3)
    LOADQ(X1, 0, 4)  LOADQ(X1, 4, 5)  LOADQ(X1, 8, 6)  LOADQ(X1, 12, 7)
    LOADQ(X2, 0, 8)  LOADQ(X2, 4, 9)  LOADQ(X2, 8, 10) LOADQ(X2, 12, 11)
    LOADQ(X3, 0, 12) LOADQ(X3, 4, 13) LOADQ(X3, 8, 14) LOADQ(X3, 12, 15)

    // numpy pairwise sum of (2x)^2 (scalar unroll-8 order); A = 0.25*it, bit-exact
    float r0 = __fmul_rn(X0[0], X0[0]), r1 = __fmul_rn(X0[1], X0[1]);
    float r2 = __fmul_rn(X0[2], X0[2]), r3 = __fmul_rn(X0[3], X0[3]);
    float r4 = __fmul_rn(X0[4], X0[4]), r5 = __fmul_rn(X0[5], X0[5]);
    float r6 = __fmul_rn(X0[6], X0[6]), r7 = __fmul_rn(X0[7], X0[7]);
#define PACCQ(V, o) \
    r0 = __fadd_rn(r0, __fmul_rn(V[(o) + 0], V[(o) + 0])); \
    r1 = __fadd_rn(r1, __fmul_rn(V[(o) + 1], V[(o) + 1])); \
    r2 = __fadd_rn(r2, __fmul_rn(V[(o) + 2], V[(o) + 2])); \
    r3 = __fadd_rn(r3, __fmul_rn(V[(o) + 3], V[(o) + 3])); \
    r4 = __fadd_rn(r4, __fmul_rn(V[(o) + 4], V[(o) + 4])); \
    r5 = __fadd_rn(r5, __fmul_rn(V[(o) + 5], V[(o) + 5])); \
    r6 = __fadd_rn(r6, __fmul_rn(V[(o) + 6], V[(o) + 6])); \
    r7 = __fadd_rn(r7, __fmul_rn(V[(o) + 7], V[(o) + 7]));
    PACCQ(X0, 8) PACCQ(X1, 0) PACCQ(X1, 8) PACCQ(X2, 0)
    PACCQ(X2, 8) PACCQ(X3, 0) PACCQ(X3, 8)
    float A = __fmul_rn(0.25f,
        __fadd_rn(__fadd_rn(__fadd_rn(r0, r1), __fadd_rn(r2, r3)),
                  __fadd_rn(__fadd_rn(r4, r5), __fadd_rn(r6, r7))));

    float m1 = 3.4e38f;
    int i1 = 0;
#define FMAQ(V, dd, o) { const float xv = V[dd]; \
        a0 = __builtin_fmaf(xv, e[(o) + (dd)      ], a0); \
        a1 = __builtin_fmaf(xv, e[(o) + (dd) +  64], a1); \
        a2 = __builtin_fmaf(xv, e[(o) + (dd) + 128], a2); \
        a3 = __builtin_fmaf(xv, e[(o) + (dd) + 192], a3); \
        a4 = __builtin_fmaf(xv, e[(o) + (dd) + 256], a4); \
        a5 = __builtin_fmaf(xv, e[(o) + (dd) + 320], a5); \
        a6 = __builtin_fmaf(xv, e[(o) + (dd) + 384], a6); \
        a7 = __builtin_fmaf(xv, e[(o) + (dd) + 448], a7); }
#define FMA_Q0(dd) FMAQ(X0, dd, 0)
#define FMA_Q1(dd) FMAQ(X1, dd, 16)
#define FMA_Q2(dd) FMAQ(X2, dd, 32)
#define FMA_Q3(dd) FMAQ(X3, dd, 48)
    for (int k = 0; k < NCODE; k += 8) {
        const float* e = emb + (size_t)k * DIM;     // wave-uniform -> scalar loads
        float a0 = 0.f, a1 = 0.f, a2 = 0.f, a3 = 0.f;
        float a4 = 0.f, a5 = 0.f, a6 = 0.f, a7 = 0.f;
        R16(FMA_Q0, 0) R16(FMA_Q1, 0) R16(FMA_Q2, 0) R16(FMA_Q3, 0)   // d ascending
        float t0 = __fadd_rn(__fsub_rn(A, a0), csum[k + 0]);
        float t1 = __fadd_rn(__fsub_rn(A, a1), csum[k + 1]);
        float t2 = __fadd_rn(__fsub_rn(A, a2), csum[k + 2]);
        float t3 = __fadd_rn(__fsub_rn(A, a3), csum[k + 3]);
        float t4 = __fadd_rn(__fsub_rn(A, a4), csum[k + 4]);
        float t5 = __fadd_rn(__fsub_rn(A, a5), csum[k + 5]);
        float t6 = __fadd_rn(__fsub_rn(A, a6), csum[k + 6]);
        float t7 = __fadd_rn(__fsub_rn(A, a7), csum[k + 7]);
        if (t0 < m1) { m1 = t0; i1 = k; }           // strict < keeps first occurrence
        if (t1 < m1) { m1 = t1; i1 = k + 1; }
        if (t2 < m1) { m1 = t2; i1 = k + 2; }
        if (t3 < m1) { m1 = t3; i1 = k + 3; }
        if (t4 < m1) { m1 = t4; i1 = k + 4; }
        if (t5 < m1) { m1 = t5; i1 = k + 5; }
        if (t6 < m1) { m1 = t6; i1 = k + 6; }
        if (t7 < m1) { m1 = t7; i1 = k + 7; }
    }
    out[OUT_CODES + row] = (float)i1;
    codes_i[row] = i1;
    atomicAdd(&h[i1], 1);                           // LDS atomic

    // z_q = x + (e - x), loss accumulation; x recovered exactly as 0.5*(2x)
    const float* e1 = emb + (size_t)i1 * DIM;
    float* zq = out + OUT_ZQ + (size_t)row * DIM;
    double lsum = 0.0;
#define ZQQ(V, b, q) { \
        float4 ev = *reinterpret_cast<const float4*>(e1 + 4 * (q)); \
        float xa = __fmul_rn(0.5f, V[(b) + 0]); \
        float xb = __fmul_rn(0.5f, V[(b) + 1]); \
        float xc = __fmul_rn(0.5f, V[(b) + 2]); \
        float xd = __fmul_rn(0.5f, V[(b) + 3]); \
        float ta = __fsub_rn(ev.x, xa); \
        float tb = __fsub_rn(ev.y, xb); \
        float tc = __fsub_rn(ev.z, xc); \
        float td = __fsub_rn(ev.w, xd); \
        float4 o; \
        o.x = __fadd_rn(xa, ta); \
        o.y = __fadd_rn(xb, tb); \
        o.z = __fadd_rn(xc, tc); \
        o.w = __fadd_rn(xd, td); \
        *reinterpret_cast<float4*>(zq + 4 * (q)) = o; \
        lsum += (double)ta * ta + (double)tb * tb + (double)tc * tc + (double)td * td; }
    ZQQ(X0, 0, 0)  ZQQ(X0, 4, 1)  ZQQ(X0, 8, 2)  ZQQ(X0, 12, 3)
    ZQQ(X1, 0, 4)  ZQQ(X1, 4, 5)  ZQQ(X1, 8, 6)  ZQQ(X1, 12, 7)
    ZQQ(X2, 0, 8)  ZQQ(X2, 4, 9)  ZQQ(X2, 8, 10) ZQQ(X2, 12, 11)
    ZQQ(X3, 0, 12) ZQQ(X3, 4, 13) ZQQ(X3, 8, 14) ZQQ(X3, 12, 15)

    for (int off = 32; off; off >>= 1) lsum += __shfl_down(lsum, off);
    int wid = threadIdx.x >> 6;
    if ((threadIdx.x & 63) == 0) ls[wid] = lsum;
    __syncthreads();                                // also orders LDS histogram
    if (threadIdx.x == 0)
        atomicAdd(lossAcc, (ls[0] + ls[1]) + (ls[2] + ls[3]));
    for (int k = threadIdx.x; k < NCODE; k += 256) {
        int c = h[k];
        if (c) atomicAdd(&counts[k], c);            // int global atomic, aggregated
    }
}

// ---- one block: exclusive scan of counts -> offsets/cursor; new_ecs + n ----
__global__ __launch_bounds__(512) void k_scan(
        const int* __restrict__ counts, int* __restrict__ offsets, int* __restrict__ cursor,
        const float* __restrict__ ecs_in, float* __restrict__ out, float* __restrict__ n_out) {
    __shared__ int sa[NCODE], sb[NCODE];
    __shared__ float red[NCODE];
    int k = threadIdx.x;
    int c = counts[k];
    sa[k] = c;
    float v = __fadd_rn(__fmul_rn(ecs_in[k], DECAY_C), __fmul_rn((float)c, OMD_C));
    out[OUT_ECS + k] = v;
    red[k] = v;
    __syncthreads();
    int* src = sa;
    int* dst = sb;
    for (int off = 1; off < NCODE; off <<= 1) {
        dst[k] = (k >= off) ? src[k - off] + src[k] : src[k];
        __syncthreads();
        int* t = src; src = dst; dst = t;
    }
    offsets[k] = src[k] - c;
    cursor[k]  = src[k] - c;
    for (int s = NCODE / 2; s > 0; s >>= 1) {
        if (k < s) red[k] += red[k + s];
        __syncthreads();
    }
    if (k == 0) n_out[0] = red[0];
}

// ---- scatter rows into code buckets ----
__global__ __launch_bounds__(256) void k_scatter(
        const int* __restrict__ codes_i, int* __restrict__ cursor, int* __restrict__ bucket) {
    int row = blockIdx.x * 256 + threadIdx.x;
    int c = codes_i[row];
    int pos = atomicAdd(&cursor[c], 1);
    bucket[pos] = row;
}

// ---- per-code segmented sum: dw[k][d] = sum of ze rows in bucket k (no atomics) ----
__global__ __launch_bounds__(256) void k_dw(
        const float* __restrict__ ze, const int* __restrict__ bucket,
        const int* __restrict__ offsets, const int* __restrict__ counts,
        float* __restrict__ dw) {
    __shared__ float p[4][DIM];
    int k = blockIdx.x;
    int w = threadIdx.x >> 6;       // wave 0..3
    int d = threadIdx.x & 63;
    int s = offsets[k];
    int n = counts[k];
    float acc0 = 0.f, acc1 = 0.f;
    int i = w;
    for (; i + 4 < n; i += 8) {     // 2 gathers in flight per wave
        int ra = bucket[s + i];
        int rb = bucket[s + i + 4];
        acc0 += ze[(size_t)ra * DIM + d];
        acc1 += ze[(size_t)rb * DIM + d];
    }
    if (i < n) acc0 += ze[(size_t)bucket[s + i] * DIM + d];
    p[w][d] = acc0 + acc1;
    __syncthreads();
    if (w == 0) dw[k * DIM + d] = (p[0][d] + p[1][d]) + (p[2][d] + p[3][d]);
}

// ---- new_ema_w, new_emb, loss ----
__global__ __launch_bounds__(256) void k_final(
        const float* __restrict__ ema_w, const float* __restrict__ dw,
        const float* __restrict__ n_ptr, const double* __restrict__ lossAcc,
        float* __restrict__ out) {
    int i = blockIdx.x * blockDim.x + threadIdx.x;
    if (i >= NCODE * DIM) return;
    int k = i >> 6;
    float w = __fadd_rn(__fmul_rn(ema_w[i], DECAY_C), __fmul_rn(dw[i], OMD_C));
    out[OUT_EMAW + i] = w;
    float n = n_ptr[0];
    float necs = out[OUT_ECS + k];
    float cs = (necs + EPS_C) / (n + (float)NCODE * EPS_C) * n;
    out[OUT_EMB + i] = w / (cs + EPS_C);
    if (i == 0) out[OUT_LOSS] = (float)(0.1 * (lossAcc[0] / (double)((size_t)NROWS * DIM)));
}

extern "C" void kernel_launch(void* const* d_in, const int* in_sizes, int n_in,
                              void* d_out, int out_size, void* d_ws, size_t ws_size,
                              hipStream_t stream) {
    const float* ze   = (const float*)d_in[0];
    const float* emb  = (const float*)d_in[1];
    const float* ecs  = (const float*)d_in[2];
    const float* emaw = (const float*)d_in[3];
    float* out = (float*)d_out;
    char* ws = (char*)d_ws;
    double* lossAcc = (double*)(ws + WS_LOSS);
    float*  n_out   = (float*)(ws + WS_N);
    int*    counts  = (int*)(ws + WS_COUNTS);
    int*    offsets = (int*)(ws + WS_OFFSETS);
    int*    cursor  = (int*)(ws + WS_CURSOR);
    float*  csum    = (float*)(ws + WS_CSUM);
    int*    codes_i = (int*)(ws + WS_CODESI);
    int*    bucket  = (int*)(ws + WS_BUCKET);
    float*  dw      = (float*)(ws + WS_DW);

    hipMemsetAsync(d_ws, 0, WS_ZERO_BYTES, stream);
    hipLaunchKernelGGL(k_csum, dim3(2), dim3(256), 0, stream, emb, csum);
    hipLaunchKernelGGL(k_scores, dim3(NROWS / 256), dim3(256), 0, stream,
                       ze, emb, csum, out, codes_i, counts, lossAcc);
    hipLaunchKernelGGL(k_scan, dim3(1), dim3(512), 0, stream,
                       counts, offsets, cursor, ecs, out, n_out);
    hipLaunchKernelGGL(k_scatter, dim3(NROWS / 256), dim3(256), 0, stream,
                       codes_i, cursor, bucket);
    hipLaunchKernelGGL(k_dw, dim3(NCODE), dim3(256), 0, stream,
                       ze, bucket, offsets, counts, dw);
    hipLaunchKernelGGL(k_final, dim3(NCODE * DIM / 256), dim3(256), 0, stream,
                       emaw, dw, n_out, lossAcc, out);
}

// Round 6
// 398.079 us; speedup vs baseline: 2.2546x; 1.0023x over previous
//
#include <hip/hip_runtime.h>
#include <math.h>

// VQ-VAE EMA vector quantizer for MI355X (gfx950).
// Argmin bit-replicates the numpy-f32 reference: dists = (sum(x*x) - (2x)@emb.T) + sum(e*e),
// numpy pairwise row-sums, BLAS sequential-FMA dot, first-occurrence argmin.
// dw/counts via counting-sort segmented reduction (no f32 global atomics).
// Round 6: pin waves_per_eu(2,2) on k_scores — the AMDGPU occupancy heuristic was
// budgeting ~52 VGPRs (8 waves/EU target) and spilling X to scratch; runtime occupancy
// is grid-limited to 2 waves/SIMD anyway, so allow 256 VGPRs.
#define NROWS 131072          // 32*4096
#define DIM 64
#define NCODE 512

// d_out float offsets (outputs concatenated flat, all float32-viewed)
#define OUT_ZQ    0
#define OUT_LOSS  8388608
#define OUT_CODES 8388609
#define OUT_ECS   8519681
#define OUT_EMAW  8520193
#define OUT_EMB   8552961

// workspace byte offsets
#define WS_LOSS    0         // double
#define WS_N       8         // float
#define WS_COUNTS  16        // int[512]
#define WS_OFFSETS 2064      // int[512]
#define WS_CURSOR  4112      // int[512]
#define WS_CSUM    6160      // float[512]
#define WS_CODESI  8208      // int[131072]
#define WS_BUCKET  532496    // int[131072]
#define WS_DW      1056784   // float[32768]
#define WS_BYTES   1187856
#define WS_ZERO_BYTES 2064   // loss + n + counts

// reference scalar constants
#define DECAY_C ((float)0.9)
#define OMD_C   ((float)(1.0 - 0.9))
#define EPS_C   ((float)1e-5)

typedef float f32x16 __attribute__((ext_vector_type(16)));

// repetition macros (all indices literal constants)
#define R4(M, b)  M(b) M((b) + 1) M((b) + 2) M((b) + 3)
#define R16(M, b) R4(M, b) R4(M, (b) + 4) R4(M, (b) + 8) R4(M, (b) + 12)

// numpy pairwise sum (scalar unroll-8 path, n=64) of v[d]*v[d], f32, no contraction.
__device__ __forceinline__ float np_pairwise64_sq(const float* v) {
    float r[8];
#pragma unroll
    for (int j = 0; j < 8; ++j) r[j] = __fmul_rn(v[j], v[j]);
#pragma unroll
    for (int b = 1; b < 8; ++b) {
#pragma unroll
        for (int j = 0; j < 8; ++j)
            r[j] = __fadd_rn(r[j], __fmul_rn(v[8 * b + j], v[8 * b + j]));
    }
    return __fadd_rn(__fadd_rn(__fadd_rn(r[0], r[1]), __fadd_rn(r[2], r[3])),
                     __fadd_rn(__fadd_rn(r[4], r[5]), __fadd_rn(r[6], r[7])));
}

// ---- csum[k] = np.sum(emb[k]*emb[k]) with numpy pairwise bits ----
__global__ void k_csum(const float* __restrict__ emb, float* __restrict__ csum) {
    int k = blockIdx.x * blockDim.x + threadIdx.x;
    if (k >= NCODE) return;
    float e[DIM];
#pragma unroll
    for (int d = 0; d < DIM; d += 4) {
        float4 v = *reinterpret_cast<const float4*>(emb + (size_t)k * DIM + d);
        e[d] = v.x; e[d + 1] = v.y; e[d + 2] = v.z; e[d + 3] = v.w;
    }
    csum[k] = np_pairwise64_sq(e);
}

// ---- fused: argmin + codes + z_q + loss + LDS histogram ----
__global__ __launch_bounds__(256, 2) __attribute__((amdgpu_waves_per_eu(2, 2)))
void k_scores(
        const float* __restrict__ ze, const float* __restrict__ emb,
        const float* __restrict__ csum, float* __restrict__ out,
        int* __restrict__ codes_i, int* __restrict__ counts,
        double* __restrict__ lossAcc) {
    __shared__ int h[NCODE];
    __shared__ double ls[4];
    for (int i = threadIdx.x; i < NCODE; i += 256) h[i] = 0;
    __syncthreads();

    int row = blockIdx.x * 256 + threadIdx.x;
    const float* x = ze + (size_t)row * DIM;
    f32x16 X0, X1, X2, X3;   // 2*x in 64 VGPRs (constant lane indices only)
#define LOADQ(V, b, q) { \
        float4 v = *reinterpret_cast<const float4*>(x + 4 * (q)); \
        V[(b) + 0] = __fadd_rn(v.x, v.x); \
        V[(b) + 1] = __fadd_rn(v.y, v.y); \
        V[(b) + 2] = __fadd_rn(v.z, v.z); \
        V[(b) + 3] = __fadd_rn(v.w, v.w); }
    LOADQ(X0, 0, 0)  LOADQ(X0, 4, 1)  LOADQ(X0, 8, 2)  LOADQ(X0, 12, 3)
    LOADQ(X1, 0, 4)  LOADQ(X1, 4, 5)  LOADQ(X1, 8, 6)  LOADQ(X1, 12, 7)
    LOADQ(X2, 0, 8)  LOADQ(X2, 4, 9)  LOADQ(X2, 8, 10) LOADQ(X2, 12, 11)
    LOADQ(X3, 0, 12) LOADQ(X3, 4, 13) LOADQ(X3, 8, 14) LOADQ(X3, 12, 15)

    // numpy pairwise sum of (2x)^2 (scalar unroll-8 order); A = 0.25*it, bit-exact
    float r0 = __fmul_rn(X0[0], X0[0]), r1 = __fmul_rn(X0[1], X0[1]);
    float r2 = __fmul_rn(X0[2], X0[2]), r3 = __fmul_rn(X0[3], X0[3]);
    float r4 = __fmul_rn(X0[4], X0[4]), r5 = __fmul_rn(X0[5], X0[5]);
    float r6 = __fmul_rn(X0[6], X0[6]), r7 = __fmul_rn(X0[7], X0[7]);
#define PACCQ(V, o) \
    r0 = __fadd_rn(r0, __fmul_rn(V[(o) + 0], V[(o) + 0])); \
    r1 = __fadd_rn(r1, __fmul_rn(V[(o) + 1], V[(o) + 1])); \
    r2 = __fadd_rn(r2, __fmul_rn(V[(o) + 2], V[(o) + 2])); \
    r3 = __fadd_rn(r3, __fmul_rn(V[(o) + 3], V[(o) + 3])); \
    r4 = __fadd_rn(r4, __fmul_rn(V[(o) + 4], V[(o) + 4])); \
    r5 = __fadd_rn(r5, __fmul_rn(V[(o) + 5], V[(o) + 5])); \
    r6 = __fadd_rn(r6, __fmul_rn(V[(o) + 6], V[(o) + 6])); \
    r7 = __fadd_rn(r7, __fmul_rn(V[(o) + 7], V[(o) + 7]));
    PACCQ(X0, 8) PACCQ(X1, 0) PACCQ(X1, 8) PACCQ(X2, 0)
    PACCQ(X2, 8) PACCQ(X3, 0) PACCQ(X3, 8)
    float A = __fmul_rn(0.25f,
        __fadd_rn(__fadd_rn(__fadd_rn(r0, r1), __fadd_rn(r2, r3)),
                  __fadd_rn(__fadd_rn(r4, r5), __fadd_rn(r6, r7))));

    float m1 = 3.4e38f;
    int i1 = 0;
#define FMAQ(V, dd, o) { const float xv = V[dd]; \
        a0 = __builtin_fmaf(xv, e[(o) + (dd)      ], a0); \
        a1 = __builtin_fmaf(xv, e[(o) + (dd) +  64], a1); \
        a2 = __builtin_fmaf(xv, e[(o) + (dd) + 128], a2); \
        a3 = __builtin_fmaf(xv, e[(o) + (dd) + 192], a3); \
        a4 = __builtin_fmaf(xv, e[(o) + (dd) + 256], a4); \
        a5 = __builtin_fmaf(xv, e[(o) + (dd) + 320], a5); \
        a6 = __builtin_fmaf(xv, e[(o) + (dd) + 384], a6); \
        a7 = __builtin_fmaf(xv, e[(o) + (dd) + 448], a7); }
#define FMA_Q0(dd) FMAQ(X0, dd, 0)
#define FMA_Q1(dd) FMAQ(X1, dd, 16)
#define FMA_Q2(dd) FMAQ(X2, dd, 32)
#define FMA_Q3(dd) FMAQ(X3, dd, 48)
    for (int k = 0; k < NCODE; k += 8) {
        const float* e = emb + (size_t)k * DIM;     // wave-uniform -> scalar loads
        float a0 = 0.f, a1 = 0.f, a2 = 0.f, a3 = 0.f;
        float a4 = 0.f, a5 = 0.f, a6 = 0.f, a7 = 0.f;
        R16(FMA_Q0, 0) R16(FMA_Q1, 0) R16(FMA_Q2, 0) R16(FMA_Q3, 0)   // d ascending
        float t0 = __fadd_rn(__fsub_rn(A, a0), csum[k + 0]);
        float t1 = __fadd_rn(__fsub_rn(A, a1), csum[k + 1]);
        float t2 = __fadd_rn(__fsub_rn(A, a2), csum[k + 2]);
        float t3 = __fadd_rn(__fsub_rn(A, a3), csum[k + 3]);
        float t4 = __fadd_rn(__fsub_rn(A, a4), csum[k + 4]);
        float t5 = __fadd_rn(__fsub_rn(A, a5), csum[k + 5]);
        float t6 = __fadd_rn(__fsub_rn(A, a6), csum[k + 6]);
        float t7 = __fadd_rn(__fsub_rn(A, a7), csum[k + 7]);
        if (t0 < m1) { m1 = t0; i1 = k; }           // strict < keeps first occurrence
        if (t1 < m1) { m1 = t1; i1 = k + 1; }
        if (t2 < m1) { m1 = t2; i1 = k + 2; }
        if (t3 < m1) { m1 = t3; i1 = k + 3; }
        if (t4 < m1) { m1 = t4; i1 = k + 4; }
        if (t5 < m1) { m1 = t5; i1 = k + 5; }
        if (t6 < m1) { m1 = t6; i1 = k + 6; }
        if (t7 < m1) { m1 = t7; i1 = k + 7; }
    }
    out[OUT_CODES + row] = (float)i1;
    codes_i[row] = i1;
    atomicAdd(&h[i1], 1);                           // LDS atomic

    // z_q = x + (e - x), loss accumulation; x recovered exactly as 0.5*(2x)
    const float* e1 = emb + (size_t)i1 * DIM;
    float* zq = out + OUT_ZQ + (size_t)row * DIM;
    double lsum = 0.0;
#define ZQQ(V, b, q) { \
        float4 ev = *reinterpret_cast<const float4*>(e1 + 4 * (q)); \
        float xa = __fmul_rn(0.5f, V[(b) + 0]); \
        float xb = __fmul_rn(0.5f, V[(b) + 1]); \
        float xc = __fmul_rn(0.5f, V[(b) + 2]); \
        float xd = __fmul_rn(0.5f, V[(b) + 3]); \
        float ta = __fsub_rn(ev.x, xa); \
        float tb = __fsub_rn(ev.y, xb); \
        float tc = __fsub_rn(ev.z, xc); \
        float td = __fsub_rn(ev.w, xd); \
        float4 o; \
        o.x = __fadd_rn(xa, ta); \
        o.y = __fadd_rn(xb, tb); \
        o.z = __fadd_rn(xc, tc); \
        o.w = __fadd_rn(xd, td); \
        *reinterpret_cast<float4*>(zq + 4 * (q)) = o; \
        lsum += (double)ta * ta + (double)tb * tb + (double)tc * tc + (double)td * td; }
    ZQQ(X0, 0, 0)  ZQQ(X0, 4, 1)  ZQQ(X0, 8, 2)  ZQQ(X0, 12, 3)
    ZQQ(X1, 0, 4)  ZQQ(X1, 4, 5)  ZQQ(X1, 8, 6)  ZQQ(X1, 12, 7)
    ZQQ(X2, 0, 8)  ZQQ(X2, 4, 9)  ZQQ(X2, 8, 10) ZQQ(X2, 12, 11)
    ZQQ(X3, 0, 12) ZQQ(X3, 4, 13) ZQQ(X3, 8, 14) ZQQ(X3, 12, 15)

    for (int off = 32; off; off >>= 1) lsum += __shfl_down(lsum, off);
    int wid = threadIdx.x >> 6;
    if ((threadIdx.x & 63) == 0) ls[wid] = lsum;
    __syncthreads();                                // also orders LDS histogram
    if (threadIdx.x == 0)
        atomicAdd(lossAcc, (ls[0] + ls[1]) + (ls[2] + ls[3]));
    for (int k = threadIdx.x; k < NCODE; k += 256) {
        int c = h[k];
        if (c) atomicAdd(&counts[k], c);            // int global atomic, aggregated
    }
}

// ---- one block: exclusive scan of counts -> offsets/cursor; new_ecs + n ----
__global__ __launch_bounds__(512) void k_scan(
        const int* __restrict__ counts, int* __restrict__ offsets, int* __restrict__ cursor,
        const float* __restrict__ ecs_in, float* __restrict__ out, float* __restrict__ n_out) {
    __shared__ int sa[NCODE], sb[NCODE];
    __shared__ float red[NCODE];
    int k = threadIdx.x;
    int c = counts[k];
    sa[k] = c;
    float v = __fadd_rn(__fmul_rn(ecs_in[k], DECAY_C), __fmul_rn((float)c, OMD_C));
    out[OUT_ECS + k] = v;
    red[k] = v;
    __syncthreads();
    int* src = sa;
    int* dst = sb;
    for (int off = 1; off < NCODE; off <<= 1) {
        dst[k] = (k >= off) ? src[k - off] + src[k] : src[k];
        __syncthreads();
        int* t = src; src = dst; dst = t;
    }
    offsets[k] = src[k] - c;
    cursor[k]  = src[k] - c;
    for (int s = NCODE / 2; s > 0; s >>= 1) {
        if (k < s) red[k] += red[k + s];
        __syncthreads();
    }
    if (k == 0) n_out[0] = red[0];
}

// ---- scatter rows into code buckets ----
__global__ __launch_bounds__(256) void k_scatter(
        const int* __restrict__ codes_i, int* __restrict__ cursor, int* __restrict__ bucket) {
    int row = blockIdx.x * 256 + threadIdx.x;
    int c = codes_i[row];
    int pos = atomicAdd(&cursor[c], 1);
    bucket[pos] = row;
}

// ---- per-code segmented sum: dw[k][d] = sum of ze rows in bucket k (no atomics) ----
__global__ __launch_bounds__(256) void k_dw(
        const float* __restrict__ ze, const int* __restrict__ bucket,
        const int* __restrict__ offsets, const int* __restrict__ counts,
        float* __restrict__ dw) {
    __shared__ float p[4][DIM];
    int k = blockIdx.x;
    int w = threadIdx.x >> 6;       // wave 0..3
    int d = threadIdx.x & 63;
    int s = offsets[k];
    int n = counts[k];
    float acc0 = 0.f, acc1 = 0.f;
    int i = w;
    for (; i + 4 < n; i += 8) {     // 2 gathers in flight per wave
        int ra = bucket[s + i];
        int rb = bucket[s + i + 4];
        acc0 += ze[(size_t)ra * DIM + d];
        acc1 += ze[(size_t)rb * DIM + d];
    }
    if (i < n) acc0 += ze[(size_t)bucket[s + i] * DIM + d];
    p[w][d] = acc0 + acc1;
    __syncthreads();
    if (w == 0) dw[k * DIM + d] = (p[0][d] + p[1][d]) + (p[2][d] + p[3][d]);
}

// ---- new_ema_w, new_emb, loss ----
__global__ __launch_bounds__(256) void k_final(
        const float* __restrict__ ema_w, const float* __restrict__ dw,
        const float* __restrict__ n_ptr, const double* __restrict__ lossAcc,
        float* __restrict__ out) {
    int i = blockIdx.x * blockDim.x + threadIdx.x;
    if (i >= NCODE * DIM) return;
    int k = i >> 6;
    float w = __fadd_rn(__fmul_rn(ema_w[i], DECAY_C), __fmul_rn(dw[i], OMD_C));
    out[OUT_EMAW + i] = w;
    float n = n_ptr[0];
    float necs = out[OUT_ECS + k];
    float cs = (necs + EPS_C) / (n + (float)NCODE * EPS_C) * n;
    out[OUT_EMB + i] = w / (cs + EPS_C);
    if (i == 0) out[OUT_LOSS] = (float)(0.1 * (lossAcc[0] / (double)((size_t)NROWS * DIM)));
}

extern "C" void kernel_launch(void* const* d_in, const int* in_sizes, int n_in,
                              void* d_out, int out_size, void* d_ws, size_t ws_size,
                              hipStream_t stream) {
    const float* ze   = (const float*)d_in[0];
    const float* emb  = (const float*)d_in[1];
    const float* ecs  = (const float*)d_in[2];
    const float* emaw = (const float*)d_in[3];
    float* out = (float*)d_out;
    char* ws = (char*)d_ws;
    double* lossAcc = (double*)(ws + WS_LOSS);
    float*  n_out   = (float*)(ws + WS_N);
    int*    counts  = (int*)(ws + WS_COUNTS);
    int*    offsets = (int*)(ws + WS_OFFSETS);
    int*    cursor  = (int*)(ws + WS_CURSOR);
    float*  csum    = (float*)(ws + WS_CSUM);
    int*    codes_i = (int*)(ws + WS_CODESI);
    int*    bucket  = (int*)(ws + WS_BUCKET);
    float*  dw      = (float*)(ws + WS_DW);

    hipMemsetAsync(d_ws, 0, WS_ZERO_BYTES, stream);
    hipLaunchKernelGGL(k_csum, dim3(2), dim3(256), 0, stream, emb, csum);
    hipLaunchKernelGGL(k_scores, dim3(NROWS / 256), dim3(256), 0, stream,
                       ze, emb, csum, out, codes_i, counts, lossAcc);
    hipLaunchKernelGGL(k_scan, dim3(1), dim3(512), 0, stream,
                       counts, offsets, cursor, ecs, out, n_out);
    hipLaunchKernelGGL(k_scatter, dim3(NROWS / 256), dim3(256), 0, stream,
                       codes_i, cursor, bucket);
    hipLaunchKernelGGL(k_dw, dim3(NCODE), dim3(256), 0, stream,
                       ze, bucket, offsets, counts, dw);
    hipLaunchKernelGGL(k_final, dim3(NCODE * DIM / 256), dim3(256), 0, stream,
                       emaw, dw, n_out, lossAcc, out);
}